// Round 1
// 112.841 us; speedup vs baseline: 1.0262x; 1.0262x over previous
//
#include <hip/hip_runtime.h>

// AdditionFFN: W1/W2 are structured one-hots, so for entry k=(a,b,c):
//   score_k = av[a] + bv[b] + carry[c]   (threshold shift cancels in softmax)
//   exp(10*score_k) = ea[a]*eb[b]*ec[c]  -> the 512-way softmax factorizes.
// With u[t] = sum_{a+b=t} ea[a]*eb[b]  (t in [0,30]) and v[j] = u[j]+u[j+16]:
//   res[j]  = (v[j]*ec0 + v[j-1]*ec1) / Z          (u[-1]=u[31]=0)
//   carry1' = (ec0*hi0 + ec1*(hi0+u[15])) / Z,  hi0 = sum_{t>=16} u[t]
//   Z = (sum ea)(sum eb)(ec0+ec1)
// out[:,:,16:] = a[:,:,16:] (position passthrough). All f32.
//
// Parallel layout: 4 lanes per row (c = lane&3); coalesced 64B per 4-lane
// group. R6 change: ALL cross-lane traffic is now DPP quad_perm (VALU),
// zero ds_bpermute. Key identity: the EBZ source lane ((x+4c)>>2)&3 equals
// (c + (x>>2))&3 — a compile-time rotation per unrolled x. 12 rotation movs
// per step replace 28 ds_bpermute; the in-range mask reduces to 6 distinct
// lane-invariant conditions (hoisted to SGPR pairs). Broadcasts use ctrl
// k*0x55; xor-butterflies use 0xB1/0x4E. This removes the lgkmcnt stalls
// that kept the kernel ~2x above its ~16 us memory roofline at the
// grid-capped 2 waves/SIMD occupancy.

#define LOG2E10 14.426950408889634f  // 10 * log2(e)

#if __has_builtin(__builtin_amdgcn_exp2f)
#define EXP2F(x) __builtin_amdgcn_exp2f(x)
#else
#define EXP2F(x) exp2f(x)
#endif

#if __has_builtin(__builtin_amdgcn_rcpf)
#define RCPF(x) __builtin_amdgcn_rcpf(x)
#else
#define RCPF(x) (1.0f / (x))
#endif

#define EBZ(x) ebz[(x) + 12]

// quad_perm DPP: dst lane i (in quad) reads src lane perm[i];
// ctrl = perm0 | perm1<<2 | perm2<<4 | perm3<<6.
//   broadcast k : ctrl = k*0x55
//   rotate by r (dst c <- src (c+r)&3): r=1:0x39  r=2:0x4E  r=3:0x93
//   xor 1: 0xB1   xor 2: 0x4E
template <int CTRL>
__device__ __forceinline__ float qdpp(float x) {
    return __int_as_float(__builtin_amdgcn_update_dpp(
        0, __float_as_int(x), CTRL, 0xF, 0xF, true));
}

__global__ __launch_bounds__(256, 2) void AdditionFFN_kernel(
    const float4* __restrict__ A, const float4* __restrict__ Bv,
    float4* __restrict__ O, int nRows)
{
    const int T = threadIdx.x;
    const int c = T & 3;                       // lane within row group
    const int row = blockIdx.x * 64 + (T >> 2);
    if (row >= nRows) return;
    const float4* a4 = A + (size_t)row * 64;   // 64 float4 per row
    const float4* b4 = Bv + (size_t)row * 64;
    float4* o4 = O + (size_t)row * 64;

    // ---- fire all loads for the whole row upfront (24 dwordx4 in flight)
    float4 AV[8], BV[8], PV[8];
    #pragma unroll
    for (int s = 0; s < 8; ++s) {
        AV[s] = a4[s * 8 + c];
        BV[s] = b4[s * 8 + c];
        PV[s] = a4[s * 8 + 4 + c];
    }

    // carry = [1,0] -> ec = exp(10*carry)
    float ec0 = EXP2F(LOG2E10);
    float ec1 = 1.0f;

    #pragma unroll  // mandatory: keeps AV[s]/BV[s]/PV[s] register-indexed
    for (int s = 0; s < 8; ++s) {
        o4[s * 8 + 4 + c] = PV[s];  // position passthrough (coalesced)

        const float4 av = AV[s], bv = BV[s];

        // exp of OWN quarter only (each exp computed once per element)
        float ea_own[4] = { EXP2F(av.x * LOG2E10), EXP2F(av.y * LOG2E10),
                            EXP2F(av.z * LOG2E10), EXP2F(av.w * LOG2E10) };
        float eb_own[4] = { EXP2F(bv.x * LOG2E10), EXP2F(bv.y * LOG2E10),
                            EXP2F(bv.z * LOG2E10), EXP2F(bv.w * LOG2E10) };

        // full ea[16] via DPP quad broadcasts (16 VALU movs, no LDS pipe)
        float ea[16];
        #pragma unroll
        for (int m = 0; m < 4; ++m) {
            ea[m]      = qdpp<0x00>(ea_own[m]);
            ea[4 + m]  = qdpp<0x55>(ea_own[m]);
            ea[8 + m]  = qdpp<0xAA>(ea_own[m]);
            ea[12 + m] = qdpp<0xFF>(ea_own[m]);
        }

        // eb rotated copies: ebr[r][m] = lane((c+r)&3)'s eb_own[m]
        float ebr[4][4];
        #pragma unroll
        for (int m = 0; m < 4; ++m) {
            ebr[0][m] = eb_own[m];
            ebr[1][m] = qdpp<0x39>(eb_own[m]);
            ebr[2][m] = qdpp<0x4E>(eb_own[m]);
            ebr[3][m] = qdpp<0x93>(eb_own[m]);
        }

        // lane-shifted zero-padded eb: EBZ(x) = eb[x+4c] if in [0,15] else 0.
        // src lane ((x+4c)>>2)&3 == (c + (x>>2))&3: a fixed rotation per x.
        // Keep-mask folds to 6 distinct lane-invariant conditions.
        float ebz[28];
        #pragma unroll
        for (int x = -12; x <= 15; ++x) {
            float vsh = ebr[(x >> 2) & 3][x & 3];  // const indices after unroll
            bool keep;
            if (x >= 0 && x <= 3)  keep = true;                  // always in range
            else if (x < 0)        keep = (c >= ((3 - x) >> 2)); // g >= 0
            else                   keep = (c <= ((15 - x) >> 2));// g <= 15
            EBZ(x) = keep ? vsh : 0.0f;
        }

        // ulo[i] = u[4c-1+i], uhi[i] = u[4c+15+i]  (i = 0..4)
        float ulo[5], uhi[5];
        #pragma unroll
        for (int i = 0; i < 5; ++i) {
            float acc = 0.0f;
            const int amax = (i + 11 < 15) ? (i + 11) : 15;  // idx >= -12
            #pragma unroll
            for (int a = 0; a <= amax; ++a) {
                acc = __builtin_fmaf(ea[a], EBZ(i - 1 - a), acc);
            }
            ulo[i] = acc;
        }
        #pragma unroll
        for (int i = 0; i < 5; ++i) {
            float acc = 0.0f;
            #pragma unroll
            for (int a = i; a < 16; ++a) {   // idx <= 15
                acc = __builtin_fmaf(ea[a], EBZ(i + 15 - a), acc);
            }
            uhi[i] = acc;
        }

        // Z = (sum ea)(sum eb)(ec0+ec1); both sums via DPP xor butterflies
        float sap = (ea_own[0] + ea_own[1]) + (ea_own[2] + ea_own[3]);
        sap += qdpp<0xB1>(sap);
        sap += qdpp<0x4E>(sap);
        float sbp = (eb_own[0] + eb_own[1]) + (eb_own[2] + eb_own[3]);
        sbp += qdpp<0xB1>(sbp);
        sbp += qdpp<0x4E>(sbp);
        const float E = ec0 + ec1;
        float Z = sap * sbp * E;
        float rZ = RCPF(Z);
        rZ = rZ * (2.0f - Z * rZ);  // one Newton step

        // carry numerator: lane c owns t = 4c+16..4c+19 (u[31] auto-zero);
        // lane 0 additionally owns the u[15]*ec1 term. Symmetric butterfly
        // keeps all 4 lanes' carry chains bit-identical.
        float hi0p = (uhi[1] + uhi[2]) + (uhi[3] + uhi[4]);
        float phi = hi0p * E + ((c == 0) ? uhi[0] * ec1 : 0.0f);
        phi += qdpp<0xB1>(phi);
        phi += qdpp<0x4E>(phi);
        float carry1 = phi * rZ;
#if __has_builtin(__builtin_amdgcn_fmed3f)
        carry1 = __builtin_amdgcn_fmed3f(carry1, 0.0f, 1.0f);  // clamp [0,1]
#else
        carry1 = fminf(fmaxf(carry1, 0.0f), 1.0f);
#endif
        float carry0 = 1.0f - carry1;

        // res[4c+k] = (v[4c+k]*ec0 + v[4c+k-1]*ec1)*rZ, v from local bins
        float vm1 = ulo[0] + uhi[0];  // v[4c-1] (c=0: u[-1]=0 -> = u[15])
        float v0 = ulo[1] + uhi[1];
        float v1 = ulo[2] + uhi[2];
        float v2 = ulo[3] + uhi[3];
        float v3 = ulo[4] + uhi[4];
        float4 r;
        r.x = (v0 * ec0 + vm1 * ec1) * rZ;
        r.y = (v1 * ec0 + v0 * ec1) * rZ;
        r.z = (v2 * ec0 + v1 * ec1) * rZ;
        r.w = (v3 * ec0 + v2 * ec1) * rZ;
        o4[s * 8 + c] = r;  // coalesced 64B per 4-lane group

        ec0 = EXP2F(carry0 * LOG2E10);
        ec1 = EXP2F(carry1 * LOG2E10);
    }
}

extern "C" void kernel_launch(void* const* d_in, const int* in_sizes, int n_in,
                              void* d_out, int out_size, void* d_ws, size_t ws_size,
                              hipStream_t stream) {
    (void)n_in; (void)out_size; (void)d_ws; (void)ws_size;
    // inputs: a_nibbles [B,8,32] f32, b_nibbles [B,8,32] f32,
    //         W1/W2_sum/W2_carry/threshold (deterministic tables — hard-coded)
    const int nRows = in_sizes[0] / 256;  // B
    const float4* A  = (const float4*)d_in[0];
    const float4* Bv = (const float4*)d_in[1];
    float4* O = (float4*)d_out;
    // 4 lanes per row: 256-thread blocks cover 64 rows; 512 blocks,
    // 2048 waves = 2 waves/SIMD (grid-capped)
    int blocks = (nRows + 63) / 64;
    AdditionFFN_kernel<<<blocks, 256, 0, stream>>>(A, Bv, O, nRows);
}

// Round 2
// 109.470 us; speedup vs baseline: 1.0578x; 1.0308x over previous
//
#include <hip/hip_runtime.h>

// AdditionFFN: W1/W2 are structured one-hots, so for entry k=(a,b,c):
//   exp(10*score_k) = ea[a]*eb[b]*ec[c]  -> the 512-way softmax factorizes.
// With u[t] = sum_{a+b=t} ea[a]*eb[b] and v[j] = u[j]+u[j+16]:
//   res[j]  = (v[j]*ec0 + v[j-1]*ec1) / Z,  Z = Sa*Sb*(ec0+ec1)
//   carry1' = (ec0*hi0 + ec1*(hi0+u[15])) / Z
//
// R7 restructure: since carry0+carry1 = 1 exactly, everything is AFFINE in
// w = ec1/(ec0+ec1):
//   res[j]  = (v[j] + w*(v[j-1]-v[j])) * rN,   rN = 1/(Sa*Sb)
//   carry1' = h + w*m,   h = hi0*rN, m = u[15]*rN
// so the 8 per-step convolutions are carry-INDEPENDENT and the serial part
// collapses to an 8-step scalar recurrence on (h_s, m_s). Layout: 32 lanes
// per row = 8 step-groups x 4 lanes. Each group computes its step's conv in
// parallel; (h,m) are exchanged all-to-all across the row's 8 groups with
// 16 intra-wave ds_swizzles (no barrier); every lane runs the tiny
// recurrence redundantly and selects its own w_s. This lifts the grid from
// 2048 waves (2/SIMD, latency-exposed) to 16384 waves with ~8x shorter
// per-wave dependency chains — the kernel should now track the ~16 us HBM
// roofline instead of sitting ~2x above it.
//
// Cross-lane: quad ops are DPP quad_perm (VALU); the one cross-quad
// exchange uses ds_swizzle BitMode (and=0x03 keeps c, or=4s' picks group).

#define LOG2E10 14.426950408889634f  // 10 * log2(e)

#if __has_builtin(__builtin_amdgcn_exp2f)
#define EXP2F(x) __builtin_amdgcn_exp2f(x)
#else
#define EXP2F(x) exp2f(x)
#endif

#if __has_builtin(__builtin_amdgcn_rcpf)
#define RCPF(x) __builtin_amdgcn_rcpf(x)
#else
#define RCPF(x) (1.0f / (x))
#endif

#define EBZ(x) ebz[(x) + 12]

// quad_perm DPP: broadcast k: ctrl=k*0x55; rotate r (dst c <- src (c+r)&3):
// r=1:0x39 r=2:0x4E r=3:0x93; xor1:0xB1 xor2:0x4E.
template <int CTRL>
__device__ __forceinline__ float qdpp(float x) {
    return __int_as_float(__builtin_amdgcn_update_dpp(
        0, __float_as_int(x), CTRL, 0xF, 0xF, true));
}

// ds_swizzle BitMode (bit15=0): src lane = ((lane & and) | or) ^ xor within
// each 32-lane group. offset = (xor<<10) | (or<<5) | and.
template <int OFF>
__device__ __forceinline__ float swz32(float x) {
    return __int_as_float(__builtin_amdgcn_ds_swizzle(__float_as_int(x), OFF));
}

__global__ __launch_bounds__(256, 4) void AdditionFFN_kernel(
    const float4* __restrict__ A, const float4* __restrict__ Bv,
    float4* __restrict__ O, int nRows)
{
    const int T = threadIdx.x;
    const int r = T & 31;                      // lane within row (32 lanes/row)
    const int c = r & 3;                       // lane within step group
    const int s = r >> 2;                      // step owned by this group
    const int row = blockIdx.x * 8 + (T >> 5); // 8 rows per 256-thread block
    if (row >= nRows) return;
    const float4* a4 = A + (size_t)row * 64;   // 64 float4 per row
    const float4* b4 = Bv + (size_t)row * 64;
    float4* o4 = O + (size_t)row * 64;

    // one step's data per group: 3 x 16B loads (64B contiguous per group)
    const float4 av = a4[s * 8 + c];
    const float4 bv = b4[s * 8 + c];
    const float4 pv = a4[s * 8 + 4 + c];
    o4[s * 8 + 4 + c] = pv;  // position passthrough, store early (frees regs)

    // exp of OWN quarter only
    float ea_own[4] = { EXP2F(av.x * LOG2E10), EXP2F(av.y * LOG2E10),
                        EXP2F(av.z * LOG2E10), EXP2F(av.w * LOG2E10) };
    float eb_own[4] = { EXP2F(bv.x * LOG2E10), EXP2F(bv.y * LOG2E10),
                        EXP2F(bv.z * LOG2E10), EXP2F(bv.w * LOG2E10) };

    // full ea[16] via DPP quad broadcasts
    float ea[16];
    #pragma unroll
    for (int m = 0; m < 4; ++m) {
        ea[m]      = qdpp<0x00>(ea_own[m]);
        ea[4 + m]  = qdpp<0x55>(ea_own[m]);
        ea[8 + m]  = qdpp<0xAA>(ea_own[m]);
        ea[12 + m] = qdpp<0xFF>(ea_own[m]);
    }

    // eb rotated copies: ebr[rot][m] = lane((c+rot)&3)'s eb_own[m]
    float ebr[4][4];
    #pragma unroll
    for (int m = 0; m < 4; ++m) {
        ebr[0][m] = eb_own[m];
        ebr[1][m] = qdpp<0x39>(eb_own[m]);
        ebr[2][m] = qdpp<0x4E>(eb_own[m]);
        ebr[3][m] = qdpp<0x93>(eb_own[m]);
    }

    // lane-shifted zero-padded eb: EBZ(x) = eb[x+4c] if in [0,15] else 0.
    float ebz[28];
    #pragma unroll
    for (int x = -12; x <= 15; ++x) {
        float vsh = ebr[(x >> 2) & 3][x & 3];  // const indices after unroll
        bool keep;
        if (x >= 0 && x <= 3)  keep = true;                  // always in range
        else if (x < 0)        keep = (c >= ((3 - x) >> 2)); // g >= 0
        else                   keep = (c <= ((15 - x) >> 2));// g <= 15
        EBZ(x) = keep ? vsh : 0.0f;
    }

    // ulo[i] = u[4c-1+i], uhi[i] = u[4c+15+i]  (i = 0..4)
    float ulo[5], uhi[5];
    #pragma unroll
    for (int i = 0; i < 5; ++i) {
        float acc = 0.0f;
        const int amax = (i + 11 < 15) ? (i + 11) : 15;  // idx >= -12
        #pragma unroll
        for (int a = 0; a <= amax; ++a) {
            acc = __builtin_fmaf(ea[a], EBZ(i - 1 - a), acc);
        }
        ulo[i] = acc;
    }
    #pragma unroll
    for (int i = 0; i < 5; ++i) {
        float acc = 0.0f;
        #pragma unroll
        for (int a = i; a < 16; ++a) {   // idx <= 15
            acc = __builtin_fmaf(ea[a], EBZ(i + 15 - a), acc);
        }
        uhi[i] = acc;
    }

    // rN = 1/(Sa*Sb); quad butterflies for Sa, Sb
    float sap = (ea_own[0] + ea_own[1]) + (ea_own[2] + ea_own[3]);
    sap += qdpp<0xB1>(sap);
    sap += qdpp<0x4E>(sap);
    float sbp = (eb_own[0] + eb_own[1]) + (eb_own[2] + eb_own[3]);
    sbp += qdpp<0xB1>(sbp);
    sbp += qdpp<0x4E>(sbp);
    float Nm = sap * sbp;
    float rN = RCPF(Nm);
    rN = rN * (2.0f - Nm * rN);  // one Newton step

    // h = hi0*rN (hi0 = sum_{t>=16} u[t]), m = u[15]*rN (u[15] in lane c=0)
    float hi0p = (uhi[1] + uhi[2]) + (uhi[3] + uhi[4]);
    hi0p += qdpp<0xB1>(hi0p);
    hi0p += qdpp<0x4E>(hi0p);
    float hs = hi0p * rN;
    float ms = qdpp<0x00>(uhi[0]) * rN;

    // all-to-all (h,m) across the row's 8 step groups (intra-wave, no barrier)
    float h0 = swz32<0x003>(hs), m0 = swz32<0x003>(ms);
    float h1 = swz32<0x083>(hs), m1 = swz32<0x083>(ms);
    float h2 = swz32<0x103>(hs), m2 = swz32<0x103>(ms);
    float h3 = swz32<0x183>(hs), m3 = swz32<0x183>(ms);
    float h4 = swz32<0x203>(hs), m4 = swz32<0x203>(ms);
    float h5 = swz32<0x283>(hs), m5 = swz32<0x283>(ms);
    float h6 = swz32<0x303>(hs), m6 = swz32<0x303>(ms);
    float h7 = swz32<0x383>(hs), m7 = swz32<0x383>(ms);

    // scalar carry recurrence, run redundantly in every lane; each lane
    // keeps the w of ITS step (compile-time-unrolled cndmask select).
    float c1 = 0.0f, wmine = 0.0f;
#define CARRY_STEP(K, HK, MK)                                        \
    {                                                                \
        float e0 = EXP2F((1.0f - c1) * LOG2E10);                     \
        float e1 = EXP2F(c1 * LOG2E10);                              \
        float E = e0 + e1;                                           \
        float rE = RCPF(E);                                          \
        rE = rE * (2.0f - E * rE);                                   \
        float w = e1 * rE;                                           \
        if (s == K) wmine = w;                                       \
        c1 = __builtin_fmaf(w, MK, HK);                              \
        c1 = fminf(fmaxf(c1, 0.0f), 1.0f);                           \
    }
    CARRY_STEP(0, h0, m0)
    CARRY_STEP(1, h1, m1)
    CARRY_STEP(2, h2, m2)
    CARRY_STEP(3, h3, m3)
    CARRY_STEP(4, h4, m4)
    CARRY_STEP(5, h5, m5)
    CARRY_STEP(6, h6, m6)
    CARRY_STEP(7, h7, m7)
#undef CARRY_STEP

    // res[4c+k] = (v[4c+k] + w*(v[4c+k-1] - v[4c+k])) * rN
    float vm1 = ulo[0] + uhi[0];  // v[4c-1] (c=0: u[-1]=0 -> = u[15])
    float v0 = ulo[1] + uhi[1];
    float v1 = ulo[2] + uhi[2];
    float v2 = ulo[3] + uhi[3];
    float v3 = ulo[4] + uhi[4];
    float4 rr;
    rr.x = __builtin_fmaf(wmine, vm1 - v0, v0) * rN;
    rr.y = __builtin_fmaf(wmine, v0 - v1, v1) * rN;
    rr.z = __builtin_fmaf(wmine, v1 - v2, v2) * rN;
    rr.w = __builtin_fmaf(wmine, v2 - v3, v3) * rN;
    o4[s * 8 + c] = rr;  // coalesced 64B per 4-lane group
}

extern "C" void kernel_launch(void* const* d_in, const int* in_sizes, int n_in,
                              void* d_out, int out_size, void* d_ws, size_t ws_size,
                              hipStream_t stream) {
    (void)n_in; (void)out_size; (void)d_ws; (void)ws_size;
    // inputs: a_nibbles [B,8,32] f32, b_nibbles [B,8,32] f32,
    //         W1/W2_sum/W2_carry/threshold (deterministic tables — hard-coded)
    const int nRows = in_sizes[0] / 256;  // B
    const float4* A  = (const float4*)d_in[0];
    const float4* Bv = (const float4*)d_in[1];
    float4* O = (float4*)d_out;
    // 32 lanes per row: 256-thread blocks cover 8 rows; 4096 blocks,
    // 16384 waves (8x the old grid), 4 resident waves/SIMD
    int blocks = (nRows + 7) / 8;
    AdditionFFN_kernel<<<blocks, 256, 0, stream>>>(A, Bv, O, nRows);
}

// Round 3
// 108.661 us; speedup vs baseline: 1.0657x; 1.0074x over previous
//
#include <hip/hip_runtime.h>

// AdditionFFN, R8: softmax factorizes (see R7 header); everything affine in
// w = ec1/(ec0+ec1):  res[j] = (v[j] + w*(v[j-1]-v[j]))*rN,  rN = 1/(Sa*Sb),
// carry1' = h + w*m,  h = hi0*rN, m = u15*rN.
//
// R8 key identity: v[j] = u[j] + u[j+16] is the 16-point CYCLIC convolution
// of ea,eb, and res is cyclic in v (v[-1] = u[15] = v[15]). Cyclic indexing
// eb[(x+4c) mod 16] == ebr[(x>>2)&3][x&3] exactly — the DPP quad-rotation
// wrap IS the mod-16 wrap, so the zero-padded ebz[28] + range masks of R7
// vanish: conv is 64 FMAs (was 140), v[4c-1] is one DPP rotate.
// hi0 = sum_{a+b>=16} ea[a]eb[b] = sum_a ea[a]*SS(16-a) via per-quarter
// suffix sums + one quad MIRROR (ctrl 0x1B: lane c <-> lane 3-c): 4 FMAs.
// Carry recurrence in sigmoid form: w = rcp(1 + exp2(L*(1-2*c1))).
//
// Layout unchanged from R7: 32 lanes/row = 8 step-groups x 4 lanes,
// (h,m) all-to-all via 16 intra-wave ds_swizzles, redundant scalar
// recurrence per lane. ~250 VALU/lane (was ~335), shorter serial tail.

#define LOG2E10 14.426950408889634f  // 10 * log2(e)

#if __has_builtin(__builtin_amdgcn_exp2f)
#define EXP2F(x) __builtin_amdgcn_exp2f(x)
#else
#define EXP2F(x) exp2f(x)
#endif

#if __has_builtin(__builtin_amdgcn_rcpf)
#define RCPF(x) __builtin_amdgcn_rcpf(x)
#else
#define RCPF(x) (1.0f / (x))
#endif

#if __has_builtin(__builtin_amdgcn_fmed3f)
#define CLAMP01(x) __builtin_amdgcn_fmed3f((x), 0.0f, 1.0f)
#else
#define CLAMP01(x) fminf(fmaxf((x), 0.0f), 1.0f)
#endif

// quad_perm DPP: broadcast k: ctrl=k*0x55; rotate r (dst c <- src (c+r)&3):
// r=1:0x39 r=2:0x4E r=3:0x93; xor1:0xB1 xor2:0x4E; mirror (c <-> 3-c): 0x1B.
template <int CTRL>
__device__ __forceinline__ float qdpp(float x) {
    return __int_as_float(__builtin_amdgcn_update_dpp(
        0, __float_as_int(x), CTRL, 0xF, 0xF, true));
}

// ds_swizzle BitMode: src lane = ((lane & and) | or) ^ xor within each
// 32-lane group. offset = (xor<<10) | (or<<5) | and.
template <int OFF>
__device__ __forceinline__ float swz32(float x) {
    return __int_as_float(__builtin_amdgcn_ds_swizzle(__float_as_int(x), OFF));
}

__global__ __launch_bounds__(256, 4) void AdditionFFN_kernel(
    const float4* __restrict__ A, const float4* __restrict__ Bv,
    float4* __restrict__ O, int nRows)
{
    const int T = threadIdx.x;
    const int r = T & 31;                      // lane within row (32 lanes/row)
    const int c = r & 3;                       // lane within step group
    const int s = r >> 2;                      // step owned by this group
    const int row = blockIdx.x * 8 + (T >> 5); // 8 rows per 256-thread block
    if (row >= nRows) return;
    const float4* a4 = A + (size_t)row * 64;   // 64 float4 per row
    const float4* b4 = Bv + (size_t)row * 64;
    float4* o4 = O + (size_t)row * 64;

    // one step's data per group: 3 x 16B loads (64B contiguous per group)
    const float4 av = a4[s * 8 + c];
    const float4 bv = b4[s * 8 + c];
    const float4 pv = a4[s * 8 + 4 + c];

    // exp of OWN quarter only
    float ea_own[4] = { EXP2F(av.x * LOG2E10), EXP2F(av.y * LOG2E10),
                        EXP2F(av.z * LOG2E10), EXP2F(av.w * LOG2E10) };
    float eb_own[4] = { EXP2F(bv.x * LOG2E10), EXP2F(bv.y * LOG2E10),
                        EXP2F(bv.z * LOG2E10), EXP2F(bv.w * LOG2E10) };

    o4[s * 8 + 4 + c] = pv;  // position passthrough (coalesced)

    // full ea[16] via DPP quad broadcasts
    float ea[16];
    #pragma unroll
    for (int m = 0; m < 4; ++m) {
        ea[m]      = qdpp<0x00>(ea_own[m]);
        ea[4 + m]  = qdpp<0x55>(ea_own[m]);
        ea[8 + m]  = qdpp<0xAA>(ea_own[m]);
        ea[12 + m] = qdpp<0xFF>(ea_own[m]);
    }

    // eb rotated copies: ebr[rot][m] = lane((c+rot)&3)'s eb_own[m];
    // ebr[(x>>2)&3][x&3] == eb[(x + 4c) mod 16]  (cyclic, no masking)
    float ebr[4][4];
    #pragma unroll
    for (int m = 0; m < 4; ++m) {
        ebr[0][m] = eb_own[m];
        ebr[1][m] = qdpp<0x39>(eb_own[m]);
        ebr[2][m] = qdpp<0x4E>(eb_own[m]);
        ebr[3][m] = qdpp<0x93>(eb_own[m]);
    }

    // cyclic convolution: v[4c+k] = sum_a ea[a] * eb[(4c+k-a) mod 16]
    float v[4];
    #pragma unroll
    for (int k = 0; k < 4; ++k) {
        float acc = 0.0f;
        #pragma unroll
        for (int a = 0; a < 16; ++a) {
            const int x = k - a;  // in [-15, 3]; two's-complement >>/& give mod 16
            acc = __builtin_fmaf(ea[a], ebr[(x >> 2) & 3][x & 3], acc);
        }
        v[k] = acc;
    }
    // v[4c-1] from neighbor lane (cyclic: lane 0 reads lane 3's v[15]=u[15])
    float vm1 = qdpp<0x93>(v[3]);

    // Sa via quad butterfly; pb rotations serve both Sb and FA
    float sap = (ea_own[0] + ea_own[1]) + (ea_own[2] + ea_own[3]);
    sap += qdpp<0xB1>(sap);
    sap += qdpp<0x4E>(sap);
    float pb = (eb_own[0] + eb_own[1]) + (eb_own[2] + eb_own[3]);
    float r1 = qdpp<0x39>(pb);   // pb of lane (c+1)&3
    float r2 = qdpp<0x4E>(pb);   // pb of lane (c+2)&3
    float r3 = qdpp<0x93>(pb);   // pb of lane (c+3)&3
    float Sb = ((pb + r1) + (r2 + r3));
    float Nm = sap * Sb;
    float rN = RCPF(Nm);
    rN = rN * (2.0f - Nm * rN);  // one Newton step

    // hi0 = sum_{a+b>=16} ea[a]*eb[b] = sum_a ea[a]*SS(16-a).
    // FA_c = sum_{q>c} pb_q (non-cyclic suffix over quarters)
    float FA = (c < 3 ? r1 : 0.0f) + (c < 2 ? r2 : 0.0f) + (c < 1 ? r3 : 0.0f);
    float t1 = eb_own[3];
    float t2 = t1 + eb_own[2];
    float t3 = t2 + eb_own[1];
    float ss1 = t3 + FA;         // SS(4c+1)
    float ss2 = t2 + FA;         // SS(4c+2)
    float ss3 = t1 + FA;         // SS(4c+3)
    float mFA = qdpp<0x1B>(FA);  // SS(16-4c)   (lane 3-c's FA)
    float mS3 = qdpp<0x1B>(ss3); // SS(15-4c)
    float mS2 = qdpp<0x1B>(ss2); // SS(14-4c)
    float mS1 = qdpp<0x1B>(ss1); // SS(13-4c)
    float hp = __builtin_fmaf(ea_own[0], mFA,
               __builtin_fmaf(ea_own[1], mS3,
               __builtin_fmaf(ea_own[2], mS2, ea_own[3] * mS1)));
    hp += qdpp<0xB1>(hp);
    hp += qdpp<0x4E>(hp);        // hi0 in all 4 lanes

    // u15 = v[15] (lane 3's v[3]); normalize step-locally
    float u15 = qdpp<0xFF>(v[3]);
    float hs = hp * rN;
    float ms = u15 * rN;

    // all-to-all (h,m) across the row's 8 step groups (intra-wave)
    float h0 = swz32<0x003>(hs), m0 = swz32<0x003>(ms);
    float h1 = swz32<0x083>(hs), m1 = swz32<0x083>(ms);
    float h2 = swz32<0x103>(hs), m2 = swz32<0x103>(ms);
    float h3 = swz32<0x183>(hs), m3 = swz32<0x183>(ms);
    float h4 = swz32<0x203>(hs), m4 = swz32<0x203>(ms);
    float h5 = swz32<0x283>(hs), m5 = swz32<0x283>(ms);
    float h6 = swz32<0x303>(hs), m6 = swz32<0x303>(ms);
    float h7 = swz32<0x383>(hs), m7 = swz32<0x383>(ms);

    // scalar carry recurrence (redundant in every lane); sigmoid form:
    // w = ec1/(ec0+ec1) = 1/(1 + exp2(LOG2E10*(1-2*c1)))
    float c1 = 0.0f, wmine = 0.0f;
#define CARRY_STEP(K, HK, MK)                                        \
    {                                                                \
        float t = __builtin_fmaf(c1, -2.0f * LOG2E10, LOG2E10);      \
        float d = 1.0f + EXP2F(t);                                   \
        float w = RCPF(d);                                           \
        if (s == K) wmine = w;                                       \
        c1 = __builtin_fmaf(w, MK, HK);                              \
        c1 = CLAMP01(c1);                                            \
    }
    CARRY_STEP(0, h0, m0)
    CARRY_STEP(1, h1, m1)
    CARRY_STEP(2, h2, m2)
    CARRY_STEP(3, h3, m3)
    CARRY_STEP(4, h4, m4)
    CARRY_STEP(5, h5, m5)
    CARRY_STEP(6, h6, m6)
    CARRY_STEP(7, h7, m7)
#undef CARRY_STEP

    // res[4c+k] = (v[4c+k] + w*(v[4c+k-1] - v[4c+k])) * rN
    float4 rr;
    rr.x = __builtin_fmaf(wmine, vm1 - v[0], v[0]) * rN;
    rr.y = __builtin_fmaf(wmine, v[0] - v[1], v[1]) * rN;
    rr.z = __builtin_fmaf(wmine, v[1] - v[2], v[2]) * rN;
    rr.w = __builtin_fmaf(wmine, v[2] - v[3], v[3]) * rN;
    o4[s * 8 + c] = rr;  // coalesced 64B per 4-lane group
}

extern "C" void kernel_launch(void* const* d_in, const int* in_sizes, int n_in,
                              void* d_out, int out_size, void* d_ws, size_t ws_size,
                              hipStream_t stream) {
    (void)n_in; (void)out_size; (void)d_ws; (void)ws_size;
    // inputs: a_nibbles [B,8,32] f32, b_nibbles [B,8,32] f32,
    //         W1/W2_sum/W2_carry/threshold (deterministic tables — hard-coded)
    const int nRows = in_sizes[0] / 256;  // B
    const float4* A  = (const float4*)d_in[0];
    const float4* Bv = (const float4*)d_in[1];
    float4* O = (float4*)d_out;
    // 32 lanes per row: 256-thread blocks cover 8 rows; 4096 blocks,
    // 16384 waves, 4 resident waves/SIMD
    int blocks = (nRows + 7) / 8;
    AdditionFFN_kernel<<<blocks, 256, 0, stream>>>(A, Bv, O, nRows);
}

// Round 4
// 107.172 us; speedup vs baseline: 1.0805x; 1.0139x over previous
//
#include <hip/hip_runtime.h>

// AdditionFFN, R9: softmax factorizes (see R7/R8 headers); affine in
// w = ec1/(ec0+ec1):  res[j] = (v[j] + w*(v[j-1]-v[j]))*rN,  rN = 1/(Sa*Sb),
// carry1' = h + w*m,  h = hi0*rN, m = u15*rN.  v = 16-pt CYCLIC conv of
// ea,eb (res cyclic in v); DPP quad-rotation wrap IS the mod-16 wrap.
//
// R9 change: OCCUPANCY. R8's VALU cut was a null result (-0.8us) -> kernel
// is latency-exposed at 4 waves/SIMD (launch_bounds(256,4) -> <=128 VGPR),
// not issue-bound: ~3us of VALU vs ~16us of traffic vs ~26us measured.
// Residency steps at 64/128 VGPRs, so force <=64 with launch_bounds(256,8)
// = 8 waves/SIMD, 2x loads in flight. Register diet to fit 64:
//   - ea[16] never materialized: conv is a-outer/k-inner with ONE broadcast
//     ea_a live at a time (same a=0..15 accumulation order per v[k] ->
//     bitwise identical to R8).
//   - eb_own aliased to ebr[0]; pb/r1..r3 as direct row sums of ebr (same
//     add order as each lane's own pb -> bit-identical across lanes).
// Peak live ~40 regs (ebr 16 + ea_own 4 + v 4 + pv 4 + ptrs + misc).
//
// Layout unchanged: 32 lanes/row = 8 step-groups x 4 lanes; (h,m)
// all-to-all via 16 intra-wave ds_swizzles; redundant scalar recurrence.

#define LOG2E10 14.426950408889634f  // 10 * log2(e)

#if __has_builtin(__builtin_amdgcn_exp2f)
#define EXP2F(x) __builtin_amdgcn_exp2f(x)
#else
#define EXP2F(x) exp2f(x)
#endif

#if __has_builtin(__builtin_amdgcn_rcpf)
#define RCPF(x) __builtin_amdgcn_rcpf(x)
#else
#define RCPF(x) (1.0f / (x))
#endif

#if __has_builtin(__builtin_amdgcn_fmed3f)
#define CLAMP01(x) __builtin_amdgcn_fmed3f((x), 0.0f, 1.0f)
#else
#define CLAMP01(x) fminf(fmaxf((x), 0.0f), 1.0f)
#endif

// quad_perm DPP: broadcast k: ctrl=k*0x55; rotate r (dst c <- src (c+r)&3):
// r=1:0x39 r=2:0x4E r=3:0x93; xor1:0xB1 xor2:0x4E; mirror (c <-> 3-c): 0x1B.
template <int CTRL>
__device__ __forceinline__ float qdpp(float x) {
    return __int_as_float(__builtin_amdgcn_update_dpp(
        0, __float_as_int(x), CTRL, 0xF, 0xF, true));
}

// ds_swizzle BitMode: src lane = ((lane & and) | or) ^ xor within each
// 32-lane group. offset = (xor<<10) | (or<<5) | and.
template <int OFF>
__device__ __forceinline__ float swz32(float x) {
    return __int_as_float(__builtin_amdgcn_ds_swizzle(__float_as_int(x), OFF));
}

__global__ __launch_bounds__(256, 8) void AdditionFFN_kernel(
    const float4* __restrict__ A, const float4* __restrict__ Bv,
    float4* __restrict__ O, int nRows)
{
    const int T = threadIdx.x;
    const int c = T & 3;                       // lane within step group
    const int s = (T >> 2) & 7;                // step owned by this group
    const int row = blockIdx.x * 8 + (T >> 5); // 8 rows per 256-thread block
    if (row >= nRows) return;
    const float4* a4 = A + (size_t)row * 64;   // 64 float4 per row
    const float4* b4 = Bv + (size_t)row * 64;
    float4* o4 = O + (size_t)row * 64;

    // one step's data per group: 3 x 16B loads (128B contiguous per group
    // across av+pv; bv reads the used half of B's row)
    const float4 av = a4[s * 8 + c];
    const float4 bv = b4[s * 8 + c];
    const float4 pv = a4[s * 8 + 4 + c];

    // exp of OWN quarter only; eb_own lives as ebr[0]
    float ea_own[4] = { EXP2F(av.x * LOG2E10), EXP2F(av.y * LOG2E10),
                        EXP2F(av.z * LOG2E10), EXP2F(av.w * LOG2E10) };
    float ebr[4][4];
    ebr[0][0] = EXP2F(bv.x * LOG2E10);
    ebr[0][1] = EXP2F(bv.y * LOG2E10);
    ebr[0][2] = EXP2F(bv.z * LOG2E10);
    ebr[0][3] = EXP2F(bv.w * LOG2E10);

    o4[s * 8 + 4 + c] = pv;  // position passthrough (coalesced, frees pv)

    // rotated eb copies: ebr[rot][m] = lane((c+rot)&3)'s eb quarter;
    // ebr[(x>>2)&3][x&3] == eb[(x + 4c) mod 16]  (cyclic, no masking)
    #pragma unroll
    for (int m = 0; m < 4; ++m) {
        ebr[1][m] = qdpp<0x39>(ebr[0][m]);
        ebr[2][m] = qdpp<0x4E>(ebr[0][m]);
        ebr[3][m] = qdpp<0x93>(ebr[0][m]);
    }

    // cyclic convolution, a-outer / k-inner with one ea broadcast live at a
    // time (v[k] still accumulates a = 0..15 in order -> bitwise = R8):
    // v[4c+k] = sum_a ea[a] * eb[(4c+k-a) mod 16]
    float v[4] = {0.0f, 0.0f, 0.0f, 0.0f};
    #pragma unroll
    for (int q = 0; q < 4; ++q) {
        #pragma unroll
        for (int m = 0; m < 4; ++m) {
            const int a = 4 * q + m;
            float ea_a;
            if (q == 0)      ea_a = qdpp<0x00>(ea_own[m]);
            else if (q == 1) ea_a = qdpp<0x55>(ea_own[m]);
            else if (q == 2) ea_a = qdpp<0xAA>(ea_own[m]);
            else             ea_a = qdpp<0xFF>(ea_own[m]);
            #pragma unroll
            for (int k = 0; k < 4; ++k) {
                const int x = k - a;  // two's-complement >>/& give mod 16
                v[k] = __builtin_fmaf(ea_a, ebr[(x >> 2) & 3][x & 3], v[k]);
            }
        }
    }
    // v[4c-1] from neighbor lane (cyclic: lane 0 reads lane 3's v[15]=u[15])
    float vm1 = qdpp<0x93>(v[3]);
    float u15 = qdpp<0xFF>(v[3]);  // v[15] broadcast to all 4 lanes

    // Sa via quad butterfly; quarter sums of eb via ebr row sums (same add
    // order as each lane's own pb -> lanes stay bit-identical)
    float sap = (ea_own[0] + ea_own[1]) + (ea_own[2] + ea_own[3]);
    sap += qdpp<0xB1>(sap);
    sap += qdpp<0x4E>(sap);
    float pb = (ebr[0][0] + ebr[0][1]) + (ebr[0][2] + ebr[0][3]);
    float r1 = (ebr[1][0] + ebr[1][1]) + (ebr[1][2] + ebr[1][3]);
    float r2 = (ebr[2][0] + ebr[2][1]) + (ebr[2][2] + ebr[2][3]);
    float r3 = (ebr[3][0] + ebr[3][1]) + (ebr[3][2] + ebr[3][3]);
    float Nm = sap * ((pb + r1) + (r2 + r3));
    float rN = RCPF(Nm);
    rN = rN * (2.0f - Nm * rN);  // one Newton step

    // hi0 = sum_{a+b>=16} ea[a]*eb[b] = sum_a ea[a]*SS(16-a).
    // FA_c = sum_{q>c} pb_q (non-cyclic suffix over quarters)
    float FA = (c < 3 ? r1 : 0.0f) + (c < 2 ? r2 : 0.0f) + (c < 1 ? r3 : 0.0f);
    float t1 = ebr[0][3];
    float t2 = t1 + ebr[0][2];
    float t3 = t2 + ebr[0][1];
    float ss1 = t3 + FA;         // SS(4c+1)
    float ss2 = t2 + FA;         // SS(4c+2)
    float ss3 = t1 + FA;         // SS(4c+3)
    float mFA = qdpp<0x1B>(FA);  // SS(16-4c)   (lane 3-c's FA)
    float mS3 = qdpp<0x1B>(ss3); // SS(15-4c)
    float mS2 = qdpp<0x1B>(ss2); // SS(14-4c)
    float mS1 = qdpp<0x1B>(ss1); // SS(13-4c)
    float hp = __builtin_fmaf(ea_own[0], mFA,
               __builtin_fmaf(ea_own[1], mS3,
               __builtin_fmaf(ea_own[2], mS2, ea_own[3] * mS1)));
    hp += qdpp<0xB1>(hp);
    hp += qdpp<0x4E>(hp);        // hi0 in all 4 lanes

    float hs = hp * rN;
    float ms = u15 * rN;

    // all-to-all (h,m) across the row's 8 step groups (intra-wave)
    float h0 = swz32<0x003>(hs), m0 = swz32<0x003>(ms);
    float h1 = swz32<0x083>(hs), m1 = swz32<0x083>(ms);
    float h2 = swz32<0x103>(hs), m2 = swz32<0x103>(ms);
    float h3 = swz32<0x183>(hs), m3 = swz32<0x183>(ms);
    float h4 = swz32<0x203>(hs), m4 = swz32<0x203>(ms);
    float h5 = swz32<0x283>(hs), m5 = swz32<0x283>(ms);
    float h6 = swz32<0x303>(hs), m6 = swz32<0x303>(ms);
    float h7 = swz32<0x383>(hs), m7 = swz32<0x383>(ms);

    // scalar carry recurrence (redundant in every lane); sigmoid form:
    // w = ec1/(ec0+ec1) = 1/(1 + exp2(LOG2E10*(1-2*c1)))
    float c1 = 0.0f, wmine = 0.0f;
#define CARRY_STEP(K, HK, MK)                                        \
    {                                                                \
        float t = __builtin_fmaf(c1, -2.0f * LOG2E10, LOG2E10);      \
        float d = 1.0f + EXP2F(t);                                   \
        float w = RCPF(d);                                           \
        if (s == K) wmine = w;                                       \
        c1 = __builtin_fmaf(w, MK, HK);                              \
        c1 = CLAMP01(c1);                                            \
    }
    CARRY_STEP(0, h0, m0)
    CARRY_STEP(1, h1, m1)
    CARRY_STEP(2, h2, m2)
    CARRY_STEP(3, h3, m3)
    CARRY_STEP(4, h4, m4)
    CARRY_STEP(5, h5, m5)
    CARRY_STEP(6, h6, m6)
    CARRY_STEP(7, h7, m7)
#undef CARRY_STEP

    // res[4c+k] = (v[4c+k] + w*(v[4c+k-1] - v[4c+k])) * rN
    float4 rr;
    rr.x = __builtin_fmaf(wmine, vm1 - v[0], v[0]) * rN;
    rr.y = __builtin_fmaf(wmine, v[0] - v[1], v[1]) * rN;
    rr.z = __builtin_fmaf(wmine, v[1] - v[2], v[2]) * rN;
    rr.w = __builtin_fmaf(wmine, v[2] - v[3], v[3]) * rN;
    o4[s * 8 + c] = rr;  // coalesced 64B per 4-lane group
}

extern "C" void kernel_launch(void* const* d_in, const int* in_sizes, int n_in,
                              void* d_out, int out_size, void* d_ws, size_t ws_size,
                              hipStream_t stream) {
    (void)n_in; (void)out_size; (void)d_ws; (void)ws_size;
    // inputs: a_nibbles [B,8,32] f32, b_nibbles [B,8,32] f32,
    //         W1/W2_sum/W2_carry/threshold (deterministic tables — hard-coded)
    const int nRows = in_sizes[0] / 256;  // B
    const float4* A  = (const float4*)d_in[0];
    const float4* Bv = (const float4*)d_in[1];
    float4* O = (float4*)d_out;
    // 32 lanes per row: 256-thread blocks cover 8 rows; 4096 blocks,
    // 16384 waves; <=64 VGPR -> 8 resident waves/SIMD
    int blocks = (nRows + 7) / 8;
    AdditionFFN_kernel<<<blocks, 256, 0, stream>>>(A, Bv, O, nRows);
}